// Round 1
// 3962.991 us; speedup vs baseline: 2.5198x; 2.5198x over previous
//
#include <hip/hip_runtime.h>
#include <hip/hip_bf16.h>
#include <math.h>

// Problem constants: N=131072 tokens, D=512, DFF=1024, 8 heads x 64,
// attention blocks of 256 tokens -> 512 blocks.
#define NTOK 131072
#define DMODEL 512
#define DFF_ 1024
#define NHEAD 8
#define HD 64
#define BLK 256
#define NB (NTOK / BLK)

typedef __hip_bfloat16 bf16;

__device__ __forceinline__ float bf_to_f(unsigned short u) {
    return __uint_as_float(((unsigned)u) << 16);
}
__device__ __forceinline__ unsigned short f_to_bf(float f) {
    bf16 h = __float2bfloat16(f);  // RNE
    return __builtin_bit_cast(unsigned short, h);
}

typedef __bf16 bfrag __attribute__((ext_vector_type(8)));  // 8 bf16 = 4 VGPR
typedef float f4t __attribute__((ext_vector_type(4)));

__device__ __forceinline__ float loadR(const float* p) { return *p; }
__device__ __forceinline__ float loadR(const ushort* p) { return bf_to_f(*p); }
__device__ __forceinline__ void storeC(float* p, float v) { *p = v; }
__device__ __forceinline__ void storeC(ushort* p, float v) { *p = f_to_bf(v); }

// async global->LDS, 16B per lane; LDS dest is wave-uniform base + lane*16
#define GLD_LDS(g, l)                                        \
    __builtin_amdgcn_global_load_lds(                        \
        (const __attribute__((address_space(1))) void*)(g),  \
        (__attribute__((address_space(3))) void*)(l), 16, 0, 0)

// =====================================================================
// bf16 MFMA GEMM (NT):  C[M,Nn] = A[M,K] * B[Nn,K]^T + bias (+resid)(gelu)
// A,B bf16 row-major over K. 128x128 tile, BK=64, 256 thr = 4 waves (2x2),
// each wave 64x64 = 4x4 frags of mfma_f32_16x16x32_bf16. Single-buffered
// LDS (m97 2-barrier structure), global_load_lds width-16 staging, linear
// LDS (T2 swizzle is null in this regime). XCD-swizzled 1-D grid.
// =====================================================================
template <typename TO, typename TR, bool RESID, bool DO_GELU>
__global__ __launch_bounds__(256) void gemm_bf16(const ushort* __restrict__ A,
                                                 const ushort* __restrict__ B,
                                                 const float* __restrict__ bias,
                                                 const TR* __restrict__ resid,
                                                 TO* __restrict__ C,
                                                 int M, int Nn, int K) {
    __shared__ __align__(16) ushort As[128 * 64];  // 16 KiB
    __shared__ __align__(16) ushort Bs[128 * 64];  // 16 KiB

    const int tid = threadIdx.x;
    const int lane = tid & 63;
    const int w = tid >> 6;
    const int wm = w >> 1, wn = w & 1;

    // XCD-aware swizzle (nwg % 8 == 0 for all our launches)
    const int ntn = Nn >> 7;
    int wg = blockIdx.x;
    const int cpx = (int)gridDim.x >> 3;
    wg = (wg & 7) * cpx + (wg >> 3);
    const int m0 = (wg / ntn) << 7;
    const int n0 = (wg % ntn) << 7;

    // staging: chunk = w*4+i covers rows chunk*8..+8, lane -> (row, kgrp)
    const int lr8 = lane >> 3;           // 0..7  : row within chunk
    const int gsc = (lane & 7) << 3;     // 0..56 : k offset (elements)

    const ushort* pa[4];
    const ushort* pb[4];
    ushort* la[4];
    ushort* lb[4];
#pragma unroll
    for (int i = 0; i < 4; ++i) {
        const int chunk = (w << 2) + i;
        const int r = (chunk << 3) + lr8;
        pa[i] = A + (size_t)(m0 + r) * K + gsc;
        pb[i] = B + (size_t)(n0 + r) * K + gsc;
        la[i] = As + (chunk << 9);  // wave-uniform (chunk*512 elems = 1 KiB)
        lb[i] = Bs + (chunk << 9);
    }

    f4t zz = {0.f, 0.f, 0.f, 0.f};
    f4t acc[4][4];
#pragma unroll
    for (int i = 0; i < 4; ++i)
#pragma unroll
        for (int j = 0; j < 4; ++j) acc[i][j] = zz;

    const int fr = lane & 15;  // fragment row (A) / col (B)
    const int kq = lane >> 4;  // k quadrant

    for (int kt = 0; kt < K; kt += 64) {
#pragma unroll
        for (int i = 0; i < 4; ++i) {
            GLD_LDS(pa[i], la[i]);
            GLD_LDS(pb[i], lb[i]);
            pa[i] += 64;
            pb[i] += 64;
        }
        __syncthreads();  // compiler drains vmcnt before s_barrier
#pragma unroll
        for (int ks = 0; ks < 2; ++ks) {
            const int sg = ((ks << 2) + kq) << 3;
            bfrag av[4], bv[4];
#pragma unroll
            for (int f = 0; f < 4; ++f) {
                av[f] = *(const bfrag*)(As + (((wm << 6) + (f << 4) + fr) << 6) + sg);
                bv[f] = *(const bfrag*)(Bs + (((wn << 6) + (f << 4) + fr) << 6) + sg);
            }
#pragma unroll
            for (int fm = 0; fm < 4; ++fm)
#pragma unroll
                for (int fn = 0; fn < 4; ++fn)
                    acc[fm][fn] = __builtin_amdgcn_mfma_f32_16x16x32_bf16(
                        av[fm], bv[fn], acc[fm][fn], 0, 0, 0);
        }
        __syncthreads();
    }

    // epilogue: C/D layout col=lane&15, row=(lane>>4)*4+reg (m89-verified)
#pragma unroll
    for (int fn = 0; fn < 4; ++fn) {
        const int col = n0 + (wn << 6) + (fn << 4) + fr;
        const float bs = bias[col];
#pragma unroll
        for (int fm = 0; fm < 4; ++fm) {
            const int rw = m0 + (wm << 6) + (fm << 4) + (kq << 2);
#pragma unroll
            for (int j = 0; j < 4; ++j) {
                float v = acc[fm][fn][j] + bs;
                const size_t off = (size_t)(rw + j) * Nn + col;
                if constexpr (RESID) v += loadR(resid + off);
                if constexpr (DO_GELU)
                    v = 0.5f * v * (1.f + erff(v * 0.70710678118654752f));
                storeC(C + off, v);
            }
        }
    }
}

// =====================================================================
// Per-(block, head) attention. qkv is [N,1536] bf16. One wg per (b,h):
// K,V staged in LDS as RAW bf16 (exact — source is bf16; halves LDS
// read bytes, the measured bottleneck) -> 73.7 KB -> 2 blocks/CU.
// thread t = query t, online-softmax over 256 keys. ctx written bf16.
// =====================================================================
__global__ __launch_bounds__(256) void attn_kernel(const ushort* __restrict__ qkv,
                                                   ushort* __restrict__ ctx) {
    __shared__ ushort Ksh[BLK][72];  // 36,864 B
    __shared__ ushort Vsh[BLK][72];  // total 73,728 B -> 2 blocks/CU
    const int b = blockIdx.x >> 3;
    const int h = blockIdx.x & 7;
    const int t = threadIdx.x;

    const ushort* qrow = qkv + (size_t)(b * BLK + t) * 1536 + h * HD;
    const ushort* krow = qrow + DMODEL;
    const ushort* vrow = qrow + 2 * DMODEL;

    float q[HD];
#pragma unroll
    for (int j = 0; j < HD; j += 4) {
        *(ushort4*)&Ksh[t][j] = *(const ushort4*)(krow + j);
        *(ushort4*)&Vsh[t][j] = *(const ushort4*)(vrow + j);
        ushort4 qv = *(const ushort4*)(qrow + j);
        q[j + 0] = bf_to_f(qv.x) * 0.125f;  // fold 1/sqrt(64) into q
        q[j + 1] = bf_to_f(qv.y) * 0.125f;
        q[j + 2] = bf_to_f(qv.z) * 0.125f;
        q[j + 3] = bf_to_f(qv.w) * 0.125f;
    }
    __syncthreads();

    float m = -1e30f, l = 0.f;
    float acc[HD];
#pragma unroll
    for (int j = 0; j < HD; ++j) acc[j] = 0.f;

    for (int s = 0; s < BLK; ++s) {
        float e0 = 0.f, e1 = 0.f, e2 = 0.f, e3 = 0.f;
#pragma unroll
        for (int j = 0; j < HD; j += 4) {
            ushort4 kv = *(const ushort4*)&Ksh[s][j];
            e0 = fmaf(q[j + 0], bf_to_f(kv.x), e0);
            e1 = fmaf(q[j + 1], bf_to_f(kv.y), e1);
            e2 = fmaf(q[j + 2], bf_to_f(kv.z), e2);
            e3 = fmaf(q[j + 3], bf_to_f(kv.w), e3);
        }
        float e = (e0 + e1) + (e2 + e3);
        float mn = fmaxf(m, e);
        float corr = __expf(m - mn);
        float p = __expf(e - mn);
        l = l * corr + p;
#pragma unroll
        for (int j = 0; j < HD; j += 4) {
            ushort4 vv = *(const ushort4*)&Vsh[s][j];
            acc[j + 0] = fmaf(acc[j + 0], corr, p * bf_to_f(vv.x));
            acc[j + 1] = fmaf(acc[j + 1], corr, p * bf_to_f(vv.y));
            acc[j + 2] = fmaf(acc[j + 2], corr, p * bf_to_f(vv.z));
            acc[j + 3] = fmaf(acc[j + 3], corr, p * bf_to_f(vv.w));
        }
        m = mn;
    }

    const float inv = 1.f / l;
    ushort* orow = ctx + (size_t)(b * BLK + t) * DMODEL + h * HD;
#pragma unroll
    for (int j = 0; j < HD; j += 4) {
        ushort4 o;
        o.x = f_to_bf(acc[j + 0] * inv);
        o.y = f_to_bf(acc[j + 1] * inv);
        o.z = f_to_bf(acc[j + 2] * inv);
        o.w = f_to_bf(acc[j + 3] * inv);
        *(ushort4*)(orow + j) = o;
    }
}

// =====================================================================
// Row LayerNorm over 512 cols. One wave per row. Optional f32 and/or
// bf16 outputs (bf16 copy feeds the next GEMM's A operand).
// =====================================================================
template <bool WF, bool WB>
__global__ __launch_bounds__(256) void ln_rows2(const float* __restrict__ in,
                                                float* __restrict__ outf,
                                                ushort* __restrict__ outb,
                                                const float* __restrict__ gg,
                                                const float* __restrict__ bb) {
    const int lane = threadIdx.x & 63;
    const int wv = threadIdx.x >> 6;
    const size_t row = (size_t)blockIdx.x * 4 + wv;
    const float* p = in + row * DMODEL + lane * 8;
    float4 a = ((const float4*)p)[0];
    float4 c = ((const float4*)p)[1];
    float s = a.x + a.y + a.z + a.w + c.x + c.y + c.z + c.w;
    float ss = a.x * a.x + a.y * a.y + a.z * a.z + a.w * a.w +
               c.x * c.x + c.y * c.y + c.z * c.z + c.w * c.w;
#pragma unroll
    for (int off = 1; off < 64; off <<= 1) {
        s += __shfl_xor(s, off, 64);
        ss += __shfl_xor(ss, off, 64);
    }
    const float mu = s * (1.f / 512.f);
    const float var = ss * (1.f / 512.f) - mu * mu;
    const float rstd = 1.f / sqrtf(var + 1e-5f);
    const int c0 = lane * 8;
    float4 g0 = *(const float4*)(gg + c0), g1 = *(const float4*)(gg + c0 + 4);
    float4 b0 = *(const float4*)(bb + c0), b1 = *(const float4*)(bb + c0 + 4);
    float4 o0, o1;
    o0.x = (a.x - mu) * rstd * g0.x + b0.x;
    o0.y = (a.y - mu) * rstd * g0.y + b0.y;
    o0.z = (a.z - mu) * rstd * g0.z + b0.z;
    o0.w = (a.w - mu) * rstd * g0.w + b0.w;
    o1.x = (c.x - mu) * rstd * g1.x + b1.x;
    o1.y = (c.y - mu) * rstd * g1.y + b1.y;
    o1.z = (c.z - mu) * rstd * g1.z + b1.z;
    o1.w = (c.w - mu) * rstd * g1.w + b1.w;
    if constexpr (WF) {
        float* qp = outf + row * DMODEL + c0;
        ((float4*)qp)[0] = o0;
        ((float4*)qp)[1] = o1;
    }
    if constexpr (WB) {
        ushort* bp = outb + row * DMODEL + c0;
        ushort4 u0, u1;
        u0.x = f_to_bf(o0.x); u0.y = f_to_bf(o0.y);
        u0.z = f_to_bf(o0.z); u0.w = f_to_bf(o0.w);
        u1.x = f_to_bf(o1.x); u1.y = f_to_bf(o1.y);
        u1.z = f_to_bf(o1.z); u1.w = f_to_bf(o1.w);
        ((ushort4*)bp)[0] = u0;
        ((ushort4*)bp)[1] = u1;
    }
}

// fp32 -> bf16 (RNE) grid-stride converter, float4/ushort4 vectorized.
__global__ __launch_bounds__(256) void cvt_f32_bf16(const float* __restrict__ in,
                                                    ushort* __restrict__ out,
                                                    int n4) {
    int i = blockIdx.x * 256 + threadIdx.x;
    const int stride = gridDim.x * 256;
    for (; i < n4; i += stride) {
        float4 v = ((const float4*)in)[i];
        ushort4 o;
        o.x = f_to_bf(v.x); o.y = f_to_bf(v.y);
        o.z = f_to_bf(v.z); o.w = f_to_bf(v.w);
        ((ushort4*)out)[i] = o;
    }
}

// =====================================================================
// Workspace plan (two layouts, chosen by ws_size at runtime):
//  roomy (ws >= 520 MiB):
//   ws:  qkv[0,384) | h f32[0,256) | hb[256,384) | xb[384,512) |
//        weights[512,517) | y2[256,512)      (MiB; phases don't overlap)
//   d_out: xb? no -- ctx bf16[0,128), then ff bf16[0,256); G4 resid = h f32.
//  tight (ws == 512 MiB):
//   ws:  qkv[0,384) | weights[384,389) | h[0,256) | hb[256,384) | ff[0,256)
//   d_out: xb[0,128) -> ctx[0,128) -> y2[0,256) (LN2 in place);
//   G4 resid = hb (bf16) since f32 h cannot stay live (768 MiB total).
// =====================================================================
extern "C" void kernel_launch(void* const* d_in, const int* in_sizes, int n_in,
                              void* d_out, int out_size, void* d_ws, size_t ws_size,
                              hipStream_t stream) {
    const float* x    = (const float*)d_in[0];
    const float* wqkv = (const float*)d_in[1];
    const float* bqkv = (const float*)d_in[2];
    const float* wo   = (const float*)d_in[3];
    const float* bo   = (const float*)d_in[4];
    const float* w1   = (const float*)d_in[5];
    const float* b1   = (const float*)d_in[6];
    const float* w2   = (const float*)d_in[7];
    const float* b2   = (const float*)d_in[8];
    const float* g1   = (const float*)d_in[9];
    const float* be1  = (const float*)d_in[10];
    const float* g2   = (const float*)d_in[11];
    const float* be2  = (const float*)d_in[12];
    float* out = (float*)d_out;

    const size_t MiB = 1ull << 20;
    char* ws = (char*)d_ws;
    char* ob = (char*)d_out;
    const bool roomy = ws_size >= 520 * MiB;

    ushort* qkv = (ushort*)ws;                // [0,384) MiB
    float*  h   = (float*)ws;                 // [0,256) (over dead qkv head)
    ushort* hb  = (ushort*)(ws + 256 * MiB);  // [256,384)
    ushort* ctx = (ushort*)ob;                // d_out [0,128)

    ushort *wqkvb, *wob, *w1b, *w2b, *xb, *ff;
    float* y2;
    if (roomy) {
        wqkvb = (ushort*)(ws + 512 * MiB);
        wob   = (ushort*)(ws + 514 * MiB);
        w1b   = (ushort*)(ws + 515 * MiB);
        w2b   = (ushort*)(ws + 516 * MiB);
        xb    = (ushort*)(ws + 384 * MiB);    // free alongside qkv
        ff    = (ushort*)ob;                  // d_out [0,256)
        y2    = (float*)(ws + 256 * MiB);     // ws [256,512), hb dead by G4
    } else {
        wqkvb = (ushort*)(ws + 384 * MiB);    // [384,389): never clobbered
        wob   = (ushort*)(ws + 386 * MiB);
        w1b   = (ushort*)(ws + 387 * MiB);
        w2b   = (ushort*)(ws + 388 * MiB);
        xb    = (ushort*)ob;                  // d_out [0,128), dead after G1
        ff    = (ushort*)ws;                  // ws [0,256), h dead after LN1
        y2    = (float*)ob;                   // d_out, LN2 in place
    }

    dim3 blk(256);
    auto cvt = [&](const float* src, ushort* dst, size_t n) {
        int n4 = (int)(n >> 2);
        int nb = (n4 + 255) / 256;
        if (nb > 4096) nb = 4096;
        cvt_f32_bf16<<<dim3(nb), blk, 0, stream>>>(src, dst, n4);
    };
    cvt(x, xb, (size_t)NTOK * DMODEL);
    cvt(wqkv, wqkvb, 1536 * 512);
    cvt(wo, wob, 512 * 512);
    cvt(w1, w1b, 1024 * 512);
    cvt(w2, w2b, 512 * 1024);

    // 1. qkv = xb @ Wqkv^T + b               [N,1536] bf16
    gemm_bf16<ushort, float, false, false><<<dim3(12 * 1024), blk, 0, stream>>>(
        xb, wqkvb, bqkv, (const float*)nullptr, qkv, NTOK, 1536, 512);
    // 2. block attention -> ctx bf16
    attn_kernel<<<dim3(NB * NHEAD), blk, 0, stream>>>(qkv, ctx);
    // 3. y = x + ctx @ Wo^T + bo -> h f32
    gemm_bf16<float, float, true, false><<<dim3(4 * 1024), blk, 0, stream>>>(
        ctx, wob, bo, x, h, NTOK, 512, 512);
    // 4. h = LN1(y): f32 in place (roomy) + bf16 copy for FFN A operand
    if (roomy)
        ln_rows2<true, true><<<dim3(NTOK / 4), blk, 0, stream>>>(h, h, hb, g1, be1);
    else
        ln_rows2<false, true><<<dim3(NTOK / 4), blk, 0, stream>>>(h, nullptr, hb, g1, be1);
    // 5. ff = gelu(hb @ W1^T + b1) -> bf16
    gemm_bf16<ushort, float, false, true><<<dim3(8 * 1024), blk, 0, stream>>>(
        hb, w1b, b1, (const float*)nullptr, ff, NTOK, 1024, 512);
    // 6. y2 = h + ff @ W2^T + b2
    if (roomy)
        gemm_bf16<float, float, true, false><<<dim3(4 * 1024), blk, 0, stream>>>(
            ff, w2b, b2, h, y2, NTOK, 512, 1024);
    else
        gemm_bf16<float, ushort, true, false><<<dim3(4 * 1024), blk, 0, stream>>>(
            ff, w2b, b2, hb, y2, NTOK, 512, 1024);
    // 7. out = LN2(y2)
    ln_rows2<true, false><<<dim3(NTOK / 4), blk, 0, stream>>>(y2, out, nullptr, g2, be2);
}

// Round 2
// 2150.180 us; speedup vs baseline: 4.6442x; 1.8431x over previous
//
#include <hip/hip_runtime.h>
#include <hip/hip_bf16.h>
#include <math.h>

// Problem constants: N=131072 tokens, D=512, DFF=1024, 8 heads x 64,
// attention blocks of 256 tokens -> 512 blocks.
#define NTOK 131072
#define DMODEL 512
#define DFF_ 1024
#define NHEAD 8
#define HD 64
#define BLK 256
#define NB (NTOK / BLK)

typedef __hip_bfloat16 bf16;

__device__ __forceinline__ float bf_to_f(unsigned short u) {
    return __uint_as_float(((unsigned)u) << 16);
}
__device__ __forceinline__ unsigned short f_to_bf(float f) {
    bf16 h = __float2bfloat16(f);  // RNE
    return __builtin_bit_cast(unsigned short, h);
}

typedef __bf16 bfrag __attribute__((ext_vector_type(8)));  // 8 bf16 = 4 VGPR
typedef float f4t __attribute__((ext_vector_type(4)));

__device__ __forceinline__ float loadR(const float* p) { return *p; }
__device__ __forceinline__ float loadR(const ushort* p) { return bf_to_f(*p); }
__device__ __forceinline__ void storeC(float* p, float v) { *p = v; }
__device__ __forceinline__ void storeC(ushort* p, float v) { *p = f_to_bf(v); }

// async global->LDS, 16B per lane; LDS dest is wave-uniform base + lane*16
#define GLD_LDS(g, l)                                        \
    __builtin_amdgcn_global_load_lds(                        \
        (const __attribute__((address_space(1))) void*)(g),  \
        (__attribute__((address_space(3))) void*)(l), 16, 0, 0)

// =====================================================================
// bf16 MFMA GEMM (NT):  C[M,Nn] = A[M,K] * B[Nn,K]^T + bias (+resid)(gelu)
// (unchanged from previous round -- harness-verified)
// =====================================================================
template <typename TO, typename TR, bool RESID, bool DO_GELU>
__global__ __launch_bounds__(256) void gemm_bf16(const ushort* __restrict__ A,
                                                 const ushort* __restrict__ B,
                                                 const float* __restrict__ bias,
                                                 const TR* __restrict__ resid,
                                                 TO* __restrict__ C,
                                                 int M, int Nn, int K) {
    __shared__ __align__(16) ushort As[128 * 64];  // 16 KiB
    __shared__ __align__(16) ushort Bs[128 * 64];  // 16 KiB

    const int tid = threadIdx.x;
    const int lane = tid & 63;
    const int w = tid >> 6;
    const int wm = w >> 1, wn = w & 1;

    // XCD-aware swizzle (nwg % 8 == 0 for all our launches)
    const int ntn = Nn >> 7;
    int wg = blockIdx.x;
    const int cpx = (int)gridDim.x >> 3;
    wg = (wg & 7) * cpx + (wg >> 3);
    const int m0 = (wg / ntn) << 7;
    const int n0 = (wg % ntn) << 7;

    const int lr8 = lane >> 3;        // 0..7  : row within chunk
    const int gsc = (lane & 7) << 3;  // 0..56 : k offset (elements)

    const ushort* pa[4];
    const ushort* pb[4];
    ushort* la[4];
    ushort* lb[4];
#pragma unroll
    for (int i = 0; i < 4; ++i) {
        const int chunk = (w << 2) + i;
        const int r = (chunk << 3) + lr8;
        pa[i] = A + (size_t)(m0 + r) * K + gsc;
        pb[i] = B + (size_t)(n0 + r) * K + gsc;
        la[i] = As + (chunk << 9);
        lb[i] = Bs + (chunk << 9);
    }

    f4t zz = {0.f, 0.f, 0.f, 0.f};
    f4t acc[4][4];
#pragma unroll
    for (int i = 0; i < 4; ++i)
#pragma unroll
        for (int j = 0; j < 4; ++j) acc[i][j] = zz;

    const int fr = lane & 15;
    const int kq = lane >> 4;

    for (int kt = 0; kt < K; kt += 64) {
#pragma unroll
        for (int i = 0; i < 4; ++i) {
            GLD_LDS(pa[i], la[i]);
            GLD_LDS(pb[i], lb[i]);
            pa[i] += 64;
            pb[i] += 64;
        }
        __syncthreads();
#pragma unroll
        for (int ks = 0; ks < 2; ++ks) {
            const int sg = ((ks << 2) + kq) << 3;
            bfrag av[4], bv[4];
#pragma unroll
            for (int f = 0; f < 4; ++f) {
                av[f] = *(const bfrag*)(As + (((wm << 6) + (f << 4) + fr) << 6) + sg);
                bv[f] = *(const bfrag*)(Bs + (((wn << 6) + (f << 4) + fr) << 6) + sg);
            }
#pragma unroll
            for (int fm = 0; fm < 4; ++fm)
#pragma unroll
                for (int fn = 0; fn < 4; ++fn)
                    acc[fm][fn] = __builtin_amdgcn_mfma_f32_16x16x32_bf16(
                        av[fm], bv[fn], acc[fm][fn], 0, 0, 0);
        }
        __syncthreads();
    }

#pragma unroll
    for (int fn = 0; fn < 4; ++fn) {
        const int col = n0 + (wn << 6) + (fn << 4) + fr;
        const float bs = bias[col];
#pragma unroll
        for (int fm = 0; fm < 4; ++fm) {
            const int rw = m0 + (wm << 6) + (fm << 4) + (kq << 2);
#pragma unroll
            for (int j = 0; j < 4; ++j) {
                float v = acc[fm][fn][j] + bs;
                const size_t off = (size_t)(rw + j) * Nn + col;
                if constexpr (RESID) v += loadR(resid + off);
                if constexpr (DO_GELU)
                    v = 0.5f * v * (1.f + erff(v * 0.70710678118654752f));
                storeC(C + off, v);
            }
        }
    }
}

// =====================================================================
// MFMA attention. One wg = one (block b, head h); 4 waves, wave w owns
// q rows w*64..w*64+63. K [256][72] and V^T [64][264] staged in padded
// LDS (reg-staged; V transposed via scalar b16 writes, 2-way free).
// Key design: S^T = mfma(A=K, B=Q) and O^T = mfma(A=V^T, B=P) keep the
// q index pinned to lane&15 end-to-end: softmax reduce = shfl_xor(16,32),
// corr/l apply in-lane, no cross-lane data movement. P goes bf16 through
// a per-wave private LDS buffer (intra-wave, no barrier); every fragment
// read matches the harness-verified GEMM pattern.
// =====================================================================
__global__ __launch_bounds__(256, 1) void attn_mfma(const ushort* __restrict__ qkv,
                                                    ushort* __restrict__ ctx) {
    __shared__ __align__(16) ushort Ks[256][72];   // 36,864 B (pad 8: b128 reads uniform)
    __shared__ __align__(16) ushort Vt[64][264];   // 33,792 B
    __shared__ __align__(16) ushort Pl[4][64][40]; // 20,480 B; total 91,136 B
    const int b = blockIdx.x >> 3;
    const int h = blockIdx.x & 7;
    const int t = threadIdx.x;
    const int lane = t & 63;
    const int w = t >> 6;
    const int fr = lane & 15;  // q (col) index within 16-block, everywhere
    const int kq = lane >> 4;  // k-quadrant / row sub-block, everywhere

    // ---- stage K rows + transposed V (once; whole 256-key block) ----
    {
        const ushort* rowp = qkv + (size_t)(b * BLK + t) * 1536 + h * HD;
#pragma unroll
        for (int c = 0; c < 8; ++c) {
            uint4 kv = *(const uint4*)(rowp + DMODEL + c * 8);
            *(uint4*)&Ks[t][c * 8] = kv;
            union { uint4 u; ushort s[8]; } vv;
            vv.u = *(const uint4*)(rowp + 2 * DMODEL + c * 8);
#pragma unroll
            for (int e = 0; e < 8; ++e) Vt[c * 8 + e][t] = vv.s[e];
        }
    }

    // ---- Q B-frags, hoisted (reused by all 4 key tiles) ----
    bfrag qb[4][2];
#pragma unroll
    for (int fn = 0; fn < 4; ++fn) {
        const ushort* qp =
            qkv + (size_t)(b * BLK + (w << 6) + (fn << 4) + fr) * 1536 + h * HD;
#pragma unroll
        for (int ks = 0; ks < 2; ++ks)
            qb[fn][ks] = *(const bfrag*)(qp + (ks << 5) + (kq << 3));
    }
    __syncthreads();

    f4t zz = {0.f, 0.f, 0.f, 0.f};
    f4t o[4][4];  // o[d-block][q-block] = O^T frags
#pragma unroll
    for (int i = 0; i < 4; ++i)
#pragma unroll
        for (int j = 0; j < 4; ++j) o[i][j] = zz;
    float m[4] = {-1e30f, -1e30f, -1e30f, -1e30f};
    float l[4] = {0.f, 0.f, 0.f, 0.f};

    for (int kt = 0; kt < 4; ++kt) {
        // --- S^T tile [64 keys][64 q]: s[key-block][q-block] ---
        f4t s[4][4];
#pragma unroll
        for (int i = 0; i < 4; ++i)
#pragma unroll
            for (int j = 0; j < 4; ++j) s[i][j] = zz;
#pragma unroll
        for (int ks = 0; ks < 2; ++ks) {
            bfrag ka[4];
#pragma unroll
            for (int fm = 0; fm < 4; ++fm)
                ka[fm] = *(const bfrag*)&Ks[(kt << 6) + (fm << 4) + fr][(ks << 5) + (kq << 3)];
#pragma unroll
            for (int fm = 0; fm < 4; ++fm)
#pragma unroll
                for (int fn = 0; fn < 4; ++fn)
                    s[fm][fn] = __builtin_amdgcn_mfma_f32_16x16x32_bf16(
                        ka[fm], qb[fn][ks], s[fm][fn], 0, 0, 0);
        }
        // --- online softmax (q == fr for both S^T and O^T frags) ---
#pragma unroll
        for (int fn = 0; fn < 4; ++fn) {
            float mx = -1e30f;
#pragma unroll
            for (int fm = 0; fm < 4; ++fm)
#pragma unroll
                for (int j = 0; j < 4; ++j) {
                    float v = s[fm][fn][j] * 0.125f;  // 1/sqrt(64)
                    s[fm][fn][j] = v;
                    mx = fmaxf(mx, v);
                }
            mx = fmaxf(mx, __shfl_xor(mx, 16));
            mx = fmaxf(mx, __shfl_xor(mx, 32));
            const float mn = fmaxf(m[fn], mx);
            const float corr = __expf(m[fn] - mn);
            m[fn] = mn;
            l[fn] *= corr;
#pragma unroll
            for (int fm = 0; fm < 4; ++fm)
#pragma unroll
                for (int j = 0; j < 4; ++j) o[fm][fn][j] *= corr;
            float ps = 0.f;
#pragma unroll
            for (int fm = 0; fm < 4; ++fm)
#pragma unroll
                for (int j = 0; j < 4; ++j) {
                    float p = __expf(s[fm][fn][j] - mn);
                    s[fm][fn][j] = p;
                    ps += p;
                }
            l[fn] += ps;  // per-lane partial (this lane's kq share); reduced at end
        }
        // --- pack P -> bf16, write to this wave's private LDS buffer ---
        // value s[fm][fn][j] is P(key = 16fm+4kq+j, q = 16fn+fr)
#pragma unroll
        for (int fn = 0; fn < 4; ++fn)
#pragma unroll
            for (int fm = 0; fm < 4; ++fm)
#pragma unroll
                for (int jj = 0; jj < 2; ++jj) {
                    unsigned u = (unsigned)f_to_bf(s[fm][fn][2 * jj]) |
                                 ((unsigned)f_to_bf(s[fm][fn][2 * jj + 1]) << 16);
                    *(unsigned*)&Pl[w][(fn << 4) + fr][(fm << 4) + (kq << 2) + 2 * jj] = u;
                }
        // --- O^T += V^T-frags x P-frags (intra-wave LDS dep, no barrier) ---
#pragma unroll
        for (int c = 0; c < 2; ++c) {
            bfrag va[4], pb[4];
#pragma unroll
            for (int fm = 0; fm < 4; ++fm)
                va[fm] = *(const bfrag*)&Vt[(fm << 4) + fr][(kt << 6) + (c << 5) + (kq << 3)];
#pragma unroll
            for (int fn = 0; fn < 4; ++fn)
                pb[fn] = *(const bfrag*)&Pl[w][(fn << 4) + fr][(c << 5) + (kq << 3)];
#pragma unroll
            for (int fm = 0; fm < 4; ++fm)
#pragma unroll
                for (int fn = 0; fn < 4; ++fn)
                    o[fm][fn] = __builtin_amdgcn_mfma_f32_16x16x32_bf16(
                        va[fm], pb[fn], o[fm][fn], 0, 0, 0);
        }
    }

    // ---- epilogue: O^T[d][q] -> ctx[q][h*64+d], 8B stores ----
    float linv[4];
#pragma unroll
    for (int fn = 0; fn < 4; ++fn) {
        float ls = l[fn];
        ls += __shfl_xor(ls, 16);
        ls += __shfl_xor(ls, 32);
        linv[fn] = 1.f / ls;
    }
#pragma unroll
    for (int fn = 0; fn < 4; ++fn) {
        const size_t qg = (size_t)(b * BLK + (w << 6) + (fn << 4) + fr);
#pragma unroll
        for (int fm = 0; fm < 4; ++fm) {
            ushort4 ov;
            ov.x = f_to_bf(o[fm][fn][0] * linv[fn]);
            ov.y = f_to_bf(o[fm][fn][1] * linv[fn]);
            ov.z = f_to_bf(o[fm][fn][2] * linv[fn]);
            ov.w = f_to_bf(o[fm][fn][3] * linv[fn]);
            *(ushort4*)(ctx + qg * DMODEL + h * HD + (fm << 4) + (kq << 2)) = ov;
        }
    }
}

// =====================================================================
// Row LayerNorm over 512 cols. One wave per row. Optional f32 and/or
// bf16 outputs. (unchanged)
// =====================================================================
template <bool WF, bool WB>
__global__ __launch_bounds__(256) void ln_rows2(const float* __restrict__ in,
                                                float* __restrict__ outf,
                                                ushort* __restrict__ outb,
                                                const float* __restrict__ gg,
                                                const float* __restrict__ bb) {
    const int lane = threadIdx.x & 63;
    const int wv = threadIdx.x >> 6;
    const size_t row = (size_t)blockIdx.x * 4 + wv;
    const float* p = in + row * DMODEL + lane * 8;
    float4 a = ((const float4*)p)[0];
    float4 c = ((const float4*)p)[1];
    float s = a.x + a.y + a.z + a.w + c.x + c.y + c.z + c.w;
    float ss = a.x * a.x + a.y * a.y + a.z * a.z + a.w * a.w +
               c.x * c.x + c.y * c.y + c.z * c.z + c.w * c.w;
#pragma unroll
    for (int off = 1; off < 64; off <<= 1) {
        s += __shfl_xor(s, off, 64);
        ss += __shfl_xor(ss, off, 64);
    }
    const float mu = s * (1.f / 512.f);
    const float var = ss * (1.f / 512.f) - mu * mu;
    const float rstd = 1.f / sqrtf(var + 1e-5f);
    const int c0 = lane * 8;
    float4 g0 = *(const float4*)(gg + c0), g1 = *(const float4*)(gg + c0 + 4);
    float4 b0 = *(const float4*)(bb + c0), b1 = *(const float4*)(bb + c0 + 4);
    float4 o0, o1;
    o0.x = (a.x - mu) * rstd * g0.x + b0.x;
    o0.y = (a.y - mu) * rstd * g0.y + b0.y;
    o0.z = (a.z - mu) * rstd * g0.z + b0.z;
    o0.w = (a.w - mu) * rstd * g0.w + b0.w;
    o1.x = (c.x - mu) * rstd * g1.x + b1.x;
    o1.y = (c.y - mu) * rstd * g1.y + b1.y;
    o1.z = (c.z - mu) * rstd * g1.z + b1.z;
    o1.w = (c.w - mu) * rstd * g1.w + b1.w;
    if constexpr (WF) {
        float* qp = outf + row * DMODEL + c0;
        ((float4*)qp)[0] = o0;
        ((float4*)qp)[1] = o1;
    }
    if constexpr (WB) {
        ushort* bp = outb + row * DMODEL + c0;
        ushort4 u0, u1;
        u0.x = f_to_bf(o0.x); u0.y = f_to_bf(o0.y);
        u0.z = f_to_bf(o0.z); u0.w = f_to_bf(o0.w);
        u1.x = f_to_bf(o1.x); u1.y = f_to_bf(o1.y);
        u1.z = f_to_bf(o1.z); u1.w = f_to_bf(o1.w);
        ((ushort4*)bp)[0] = u0;
        ((ushort4*)bp)[1] = u1;
    }
}

// fp32 -> bf16 (RNE) grid-stride converter, float4/ushort4 vectorized.
__global__ __launch_bounds__(256) void cvt_f32_bf16(const float* __restrict__ in,
                                                    ushort* __restrict__ out,
                                                    int n4) {
    int i = blockIdx.x * 256 + threadIdx.x;
    const int stride = gridDim.x * 256;
    for (; i < n4; i += stride) {
        float4 v = ((const float4*)in)[i];
        ushort4 o;
        o.x = f_to_bf(v.x); o.y = f_to_bf(v.y);
        o.z = f_to_bf(v.z); o.w = f_to_bf(v.w);
        ((ushort4*)out)[i] = o;
    }
}

// =====================================================================
// Workspace plan (unchanged; two layouts chosen by ws_size at runtime).
// =====================================================================
extern "C" void kernel_launch(void* const* d_in, const int* in_sizes, int n_in,
                              void* d_out, int out_size, void* d_ws, size_t ws_size,
                              hipStream_t stream) {
    const float* x    = (const float*)d_in[0];
    const float* wqkv = (const float*)d_in[1];
    const float* bqkv = (const float*)d_in[2];
    const float* wo   = (const float*)d_in[3];
    const float* bo   = (const float*)d_in[4];
    const float* w1   = (const float*)d_in[5];
    const float* b1   = (const float*)d_in[6];
    const float* w2   = (const float*)d_in[7];
    const float* b2   = (const float*)d_in[8];
    const float* g1   = (const float*)d_in[9];
    const float* be1  = (const float*)d_in[10];
    const float* g2   = (const float*)d_in[11];
    const float* be2  = (const float*)d_in[12];
    float* out = (float*)d_out;

    const size_t MiB = 1ull << 20;
    char* ws = (char*)d_ws;
    char* ob = (char*)d_out;
    const bool roomy = ws_size >= 520 * MiB;

    ushort* qkv = (ushort*)ws;                // [0,384) MiB
    float*  h   = (float*)ws;                 // [0,256) (over dead qkv head)
    ushort* hb  = (ushort*)(ws + 256 * MiB);  // [256,384)
    ushort* ctx = (ushort*)ob;                // d_out [0,128)

    ushort *wqkvb, *wob, *w1b, *w2b, *xb, *ff;
    float* y2;
    if (roomy) {
        wqkvb = (ushort*)(ws + 512 * MiB);
        wob   = (ushort*)(ws + 514 * MiB);
        w1b   = (ushort*)(ws + 515 * MiB);
        w2b   = (ushort*)(ws + 516 * MiB);
        xb    = (ushort*)(ws + 384 * MiB);
        ff    = (ushort*)ob;
        y2    = (float*)(ws + 256 * MiB);
    } else {
        wqkvb = (ushort*)(ws + 384 * MiB);
        wob   = (ushort*)(ws + 386 * MiB);
        w1b   = (ushort*)(ws + 387 * MiB);
        w2b   = (ushort*)(ws + 388 * MiB);
        xb    = (ushort*)ob;
        ff    = (ushort*)ws;
        y2    = (float*)ob;
    }

    dim3 blk(256);
    auto cvt = [&](const float* src, ushort* dst, size_t n) {
        int n4 = (int)(n >> 2);
        int nb = (n4 + 255) / 256;
        if (nb > 4096) nb = 4096;
        cvt_f32_bf16<<<dim3(nb), blk, 0, stream>>>(src, dst, n4);
    };
    cvt(x, xb, (size_t)NTOK * DMODEL);
    cvt(wqkv, wqkvb, 1536 * 512);
    cvt(wo, wob, 512 * 512);
    cvt(w1, w1b, 1024 * 512);
    cvt(w2, w2b, 512 * 1024);

    // 1. qkv = xb @ Wqkv^T + b               [N,1536] bf16
    gemm_bf16<ushort, float, false, false><<<dim3(12 * 1024), blk, 0, stream>>>(
        xb, wqkvb, bqkv, (const float*)nullptr, qkv, NTOK, 1536, 512);
    // 2. block attention (MFMA) -> ctx bf16
    attn_mfma<<<dim3(NB * NHEAD), blk, 0, stream>>>(qkv, ctx);
    // 3. y = x + ctx @ Wo^T + bo -> h f32
    gemm_bf16<float, float, true, false><<<dim3(4 * 1024), blk, 0, stream>>>(
        ctx, wob, bo, x, h, NTOK, 512, 512);
    // 4. h = LN1(y): f32 in place (roomy) + bf16 copy for FFN A operand
    if (roomy)
        ln_rows2<true, true><<<dim3(NTOK / 4), blk, 0, stream>>>(h, h, hb, g1, be1);
    else
        ln_rows2<false, true><<<dim3(NTOK / 4), blk, 0, stream>>>(h, nullptr, hb, g1, be1);
    // 5. ff = gelu(hb @ W1^T + b1) -> bf16
    gemm_bf16<ushort, float, false, true><<<dim3(8 * 1024), blk, 0, stream>>>(
        hb, w1b, b1, (const float*)nullptr, ff, NTOK, 1024, 512);
    // 6. y2 = h + ff @ W2^T + b2
    if (roomy)
        gemm_bf16<float, float, true, false><<<dim3(4 * 1024), blk, 0, stream>>>(
            ff, w2b, b2, h, y2, NTOK, 512, 1024);
    else
        gemm_bf16<float, ushort, true, false><<<dim3(4 * 1024), blk, 0, stream>>>(
            ff, w2b, b2, hb, y2, NTOK, 512, 1024);
    // 7. out = LN2(y2)
    ln_rows2<true, false><<<dim3(NTOK / 4), blk, 0, stream>>>(y2, out, nullptr, g2, be2);
}

// Round 3
// 1807.892 us; speedup vs baseline: 5.5235x; 1.1893x over previous
//
#include <hip/hip_runtime.h>
#include <hip/hip_bf16.h>
#include <math.h>

// Problem constants: N=131072 tokens, D=512, DFF=1024, 8 heads x 64,
// attention blocks of 256 tokens -> 512 blocks.
#define NTOK 131072
#define DMODEL 512
#define DFF_ 1024
#define NHEAD 8
#define HD 64
#define BLK 256
#define NB (NTOK / BLK)

typedef __hip_bfloat16 bf16;

__device__ __forceinline__ float bf_to_f(unsigned short u) {
    return __uint_as_float(((unsigned)u) << 16);
}
__device__ __forceinline__ unsigned short f_to_bf(float f) {
    bf16 h = __float2bfloat16(f);  // RNE
    return __builtin_bit_cast(unsigned short, h);
}

typedef __bf16 bfrag __attribute__((ext_vector_type(8)));  // 8 bf16 = 4 VGPR
typedef float f4t __attribute__((ext_vector_type(4)));

__device__ __forceinline__ float loadR(const float* p) { return *p; }
__device__ __forceinline__ float loadR(const ushort* p) { return bf_to_f(*p); }
__device__ __forceinline__ void storeC(float* p, float v) { *p = v; }
__device__ __forceinline__ void storeC(ushort* p, float v) { *p = f_to_bf(v); }

// async global->LDS, 16B per lane; LDS dest is wave-uniform base + lane*16
#define GLD_LDS(g, l)                                        \
    __builtin_amdgcn_global_load_lds(                        \
        (const __attribute__((address_space(1))) void*)(g),  \
        (__attribute__((address_space(3))) void*)(l), 16, 0, 0)

// =====================================================================
// 8-phase 256x256 bf16 MFMA GEMM (NT): C = A[M,K] * B[Nn,K]^T + bias
// (+resid)(gelu).  512 thr = 8 waves (2M x 4N), per-wave 128x64 output.
// BK=64; LDS = 2 dbuf x {A,B} x 2 half x [128][64] bf16 = 128 KiB.
// Schedule (derived ledger, audited):
//   iteration computes tiles U=tt (phases 0-3, dbuf0) and V=tt+1
//   (phases 4-7, dbuf1). Phase p<4 stages ht[p] of tile tt+1 -> dbuf1
//   (idle); p>=4 stages ht[p-4] of tile tt+2 -> dbuf0 (freed at p3).
//   Landed-check: single asm "s_waitcnt vmcnt(2); s_barrier" at p0/p4
//   (the 2 allowed-outstanding are the ht just issued). No full drain
//   in steady state. Trailing s_barrier per phase keeps waves locked;
//   compiler inserts lgkmcnt before MFMA use (visible dep).
// LDS swizzle (T2, m214-verified pattern unit^=(row&7)): read unit
//   u' = u ^ (row&7); staging keeps LDS linear and inverse-swizzles the
//   per-lane GLOBAL source (rule #21 both-sides). Kills the 16-way
//   conflict of row-stride-128B fragment reads.
// =====================================================================
template <typename TO, typename TR, bool RESID, bool DO_GELU>
__global__ __launch_bounds__(512, 2) void gemm8p(const ushort* __restrict__ A,
                                                 const ushort* __restrict__ B,
                                                 const float* __restrict__ bias,
                                                 const TR* __restrict__ resid,
                                                 TO* __restrict__ C,
                                                 int M, int Nn, int K) {
    __shared__ __align__(16) ushort Ls[2][2][2][128][64];  // 131072 B

    const int tid = threadIdx.x;
    const int lane = tid & 63;
    const int w = tid >> 6;    // 0..7
    const int wm = w >> 2;     // 0..1 (row half)
    const int wn = w & 3;      // 0..3 (col quarter)
    const int fr = lane & 15;  // fragment row/col index
    const int kq = lane >> 4;  // k quadrant
    // staging lane geometry: row-in-seg + inverse-swizzled global unit
    const int sr = lane >> 3;            // 0..7
    const int su = (lane & 7) ^ sr;      // global 16B-unit (inverse swz)

    // XCD-aware swizzle (grid % 8 == 0 for all launches here)
    const int ntn = Nn >> 8;
    int wg = blockIdx.x;
    const int cpx = (int)gridDim.x >> 3;
    wg = (wg & 7) * cpx + (wg >> 3);
    const int m0 = (wg / ntn) << 8;
    const int n0 = (wg % ntn) << 8;

    // stage one half-tile (16 KiB): ht = (mat, h). 2 gld_lds per thread.
    auto stage_ht = [&](int db, int mat, int t, int h) {
#pragma unroll
        for (int i = 0; i < 2; ++i) {
            const int seg = (w << 1) + i;                 // 0..15
            const int rr = (h << 7) + (seg << 3) + sr;    // tile-local row
            const ushort* gp = (mat ? B : A) +
                (size_t)((mat ? n0 : m0) + rr) * K + (t << 6) + (su << 3);
            GLD_LDS(gp, &Ls[db][mat][h][seg << 3][0]);
        }
    };

    f4t zz = {0.f, 0.f, 0.f, 0.f};
    f4t acc[8][4];
#pragma unroll
    for (int i = 0; i < 8; ++i)
#pragma unroll
        for (int j = 0; j < 4; ++j) acc[i][j] = zz;

    const int NT = K >> 6;
    // prologue: tile 0 -> dbuf0 (8 loads in flight)
    stage_ht(0, 0, 0, 0); stage_ht(0, 0, 0, 1);
    stage_ht(0, 1, 0, 0); stage_ht(0, 1, 0, 1);

    for (int tt = 0; tt < NT; tt += 2) {
#pragma unroll
        for (int p = 0; p < 8; ++p) {
            const int hi = p >> 2;       // 0: compute tt, 1: compute tt+1
            const int q = p & 3;         // phase-in-tile
            const int mh = q & 1;        // output row-half quadrant
            const int ks = q >> 1;       // k-slice
            const int dc = hi;           // compute dbuf (tt even)
            const int ds_ = 1 - hi;      // staged dbuf
            const int st = tt + 1 + hi;  // staged tile
            const bool do_stage = st < NT;  // wave-uniform

            if (q == 0) {
                // landed-check phase: issue next ht first, then counted wait
                if (do_stage) {
                    stage_ht(ds_, 0, st, 0);  // ht0 = (A, half0)
                    asm volatile("s_waitcnt vmcnt(2)\n\ts_barrier" ::: "memory");
                } else {
                    asm volatile("s_waitcnt vmcnt(0)\n\ts_barrier" ::: "memory");
                }
            }

            // ds-read this quadrant's fragments (swizzled unit)
            bfrag av[4], bv[4];
            const int uu = ((((ks << 2) | kq)) ^ (fr & 7)) << 3;
#pragma unroll
            for (int f = 0; f < 4; ++f) {
                const int rA = (wm << 7) + (mh << 6) + (f << 4) + fr;
                av[f] = *(const bfrag*)&Ls[dc][0][rA >> 7][rA & 127][uu];
                const int rB = (wn << 6) + (f << 4) + fr;
                bv[f] = *(const bfrag*)&Ls[dc][1][rB >> 7][rB & 127][uu];
            }
            if (q != 0 && do_stage) {
                // ht q: (mat = q>>1, half = q&1)
                stage_ht(ds_, q >> 1, st, q & 1);
            }

            __builtin_amdgcn_s_setprio(1);
#pragma unroll
            for (int f = 0; f < 4; ++f)
#pragma unroll
                for (int fn = 0; fn < 4; ++fn)
                    acc[(mh << 2) + f][fn] = __builtin_amdgcn_mfma_f32_16x16x32_bf16(
                        av[f], bv[fn], acc[(mh << 2) + f][fn], 0, 0, 0);
            __builtin_amdgcn_s_setprio(0);
            __builtin_amdgcn_s_barrier();
        }
    }

    // epilogue: C/D layout col=lane&15, row=(lane>>4)*4+reg (m89-verified)
#pragma unroll
    for (int fn = 0; fn < 4; ++fn) {
        const int col = n0 + (wn << 6) + (fn << 4) + fr;
        const float bs = bias[col];
#pragma unroll
        for (int fm = 0; fm < 8; ++fm) {
            const int rw = m0 + (wm << 7) + (fm << 4) + (kq << 2);
#pragma unroll
            for (int j = 0; j < 4; ++j) {
                float v = acc[fm][fn][j] + bs;
                const size_t off = (size_t)(rw + j) * Nn + col;
                if constexpr (RESID) v += loadR(resid + off);
                if constexpr (DO_GELU)
                    v = 0.5f * v * (1.f + erff(v * 0.70710678118654752f));
                storeC(C + off, v);
            }
        }
    }
}

// =====================================================================
// MFMA attention (unchanged from round 2 -- harness-verified).
// One wg = (block b, head h); 4 waves; S^T = mfma(K,Q), O^T = mfma(Vt,P)
// keep q pinned to lane&15; P via per-wave private LDS, bf16.
// =====================================================================
__global__ __launch_bounds__(256, 1) void attn_mfma(const ushort* __restrict__ qkv,
                                                    ushort* __restrict__ ctx) {
    __shared__ __align__(16) ushort Ks[256][72];
    __shared__ __align__(16) ushort Vt[64][264];
    __shared__ __align__(16) ushort Pl[4][64][40];
    const int b = blockIdx.x >> 3;
    const int h = blockIdx.x & 7;
    const int t = threadIdx.x;
    const int lane = t & 63;
    const int w = t >> 6;
    const int fr = lane & 15;
    const int kq = lane >> 4;

    {
        const ushort* rowp = qkv + (size_t)(b * BLK + t) * 1536 + h * HD;
#pragma unroll
        for (int c = 0; c < 8; ++c) {
            uint4 kv = *(const uint4*)(rowp + DMODEL + c * 8);
            *(uint4*)&Ks[t][c * 8] = kv;
            union { uint4 u; ushort s[8]; } vv;
            vv.u = *(const uint4*)(rowp + 2 * DMODEL + c * 8);
#pragma unroll
            for (int e = 0; e < 8; ++e) Vt[c * 8 + e][t] = vv.s[e];
        }
    }

    bfrag qb[4][2];
#pragma unroll
    for (int fn = 0; fn < 4; ++fn) {
        const ushort* qp =
            qkv + (size_t)(b * BLK + (w << 6) + (fn << 4) + fr) * 1536 + h * HD;
#pragma unroll
        for (int ks = 0; ks < 2; ++ks)
            qb[fn][ks] = *(const bfrag*)(qp + (ks << 5) + (kq << 3));
    }
    __syncthreads();

    f4t zz = {0.f, 0.f, 0.f, 0.f};
    f4t o[4][4];
#pragma unroll
    for (int i = 0; i < 4; ++i)
#pragma unroll
        for (int j = 0; j < 4; ++j) o[i][j] = zz;
    float m[4] = {-1e30f, -1e30f, -1e30f, -1e30f};
    float l[4] = {0.f, 0.f, 0.f, 0.f};

    for (int kt = 0; kt < 4; ++kt) {
        f4t s[4][4];
#pragma unroll
        for (int i = 0; i < 4; ++i)
#pragma unroll
            for (int j = 0; j < 4; ++j) s[i][j] = zz;
#pragma unroll
        for (int ks = 0; ks < 2; ++ks) {
            bfrag ka[4];
#pragma unroll
            for (int fm = 0; fm < 4; ++fm)
                ka[fm] = *(const bfrag*)&Ks[(kt << 6) + (fm << 4) + fr][(ks << 5) + (kq << 3)];
#pragma unroll
            for (int fm = 0; fm < 4; ++fm)
#pragma unroll
                for (int fn = 0; fn < 4; ++fn)
                    s[fm][fn] = __builtin_amdgcn_mfma_f32_16x16x32_bf16(
                        ka[fm], qb[fn][ks], s[fm][fn], 0, 0, 0);
        }
#pragma unroll
        for (int fn = 0; fn < 4; ++fn) {
            float mx = -1e30f;
#pragma unroll
            for (int fm = 0; fm < 4; ++fm)
#pragma unroll
                for (int j = 0; j < 4; ++j) {
                    float v = s[fm][fn][j] * 0.125f;
                    s[fm][fn][j] = v;
                    mx = fmaxf(mx, v);
                }
            mx = fmaxf(mx, __shfl_xor(mx, 16));
            mx = fmaxf(mx, __shfl_xor(mx, 32));
            const float mn = fmaxf(m[fn], mx);
            const float corr = __expf(m[fn] - mn);
            m[fn] = mn;
            l[fn] *= corr;
#pragma unroll
            for (int fm = 0; fm < 4; ++fm)
#pragma unroll
                for (int j = 0; j < 4; ++j) o[fm][fn][j] *= corr;
            float ps = 0.f;
#pragma unroll
            for (int fm = 0; fm < 4; ++fm)
#pragma unroll
                for (int j = 0; j < 4; ++j) {
                    float p = __expf(s[fm][fn][j] - mn);
                    s[fm][fn][j] = p;
                    ps += p;
                }
            l[fn] += ps;
        }
#pragma unroll
        for (int fn = 0; fn < 4; ++fn)
#pragma unroll
            for (int fm = 0; fm < 4; ++fm)
#pragma unroll
                for (int jj = 0; jj < 2; ++jj) {
                    unsigned u = (unsigned)f_to_bf(s[fm][fn][2 * jj]) |
                                 ((unsigned)f_to_bf(s[fm][fn][2 * jj + 1]) << 16);
                    *(unsigned*)&Pl[w][(fn << 4) + fr][(fm << 4) + (kq << 2) + 2 * jj] = u;
                }
#pragma unroll
        for (int c = 0; c < 2; ++c) {
            bfrag va[4], pb[4];
#pragma unroll
            for (int fm = 0; fm < 4; ++fm)
                va[fm] = *(const bfrag*)&Vt[(fm << 4) + fr][(kt << 6) + (c << 5) + (kq << 3)];
#pragma unroll
            for (int fn = 0; fn < 4; ++fn)
                pb[fn] = *(const bfrag*)&Pl[w][(fn << 4) + fr][(c << 5) + (kq << 3)];
#pragma unroll
            for (int fm = 0; fm < 4; ++fm)
#pragma unroll
                for (int fn = 0; fn < 4; ++fn)
                    o[fm][fn] = __builtin_amdgcn_mfma_f32_16x16x32_bf16(
                        va[fm], pb[fn], o[fm][fn], 0, 0, 0);
        }
    }

    float linv[4];
#pragma unroll
    for (int fn = 0; fn < 4; ++fn) {
        float ls = l[fn];
        ls += __shfl_xor(ls, 16);
        ls += __shfl_xor(ls, 32);
        linv[fn] = 1.f / ls;
    }
#pragma unroll
    for (int fn = 0; fn < 4; ++fn) {
        const size_t qg = (size_t)(b * BLK + (w << 6) + (fn << 4) + fr);
#pragma unroll
        for (int fm = 0; fm < 4; ++fm) {
            ushort4 ov;
            ov.x = f_to_bf(o[fm][fn][0] * linv[fn]);
            ov.y = f_to_bf(o[fm][fn][1] * linv[fn]);
            ov.z = f_to_bf(o[fm][fn][2] * linv[fn]);
            ov.w = f_to_bf(o[fm][fn][3] * linv[fn]);
            *(ushort4*)(ctx + qg * DMODEL + h * HD + (fm << 4) + (kq << 2)) = ov;
        }
    }
}

// =====================================================================
// Row LayerNorm over 512 cols. One wave per row. Optional f32 / bf16 out.
// =====================================================================
template <bool WF, bool WB>
__global__ __launch_bounds__(256) void ln_rows2(const float* __restrict__ in,
                                                float* __restrict__ outf,
                                                ushort* __restrict__ outb,
                                                const float* __restrict__ gg,
                                                const float* __restrict__ bb) {
    const int lane = threadIdx.x & 63;
    const int wv = threadIdx.x >> 6;
    const size_t row = (size_t)blockIdx.x * 4 + wv;
    const float* p = in + row * DMODEL + lane * 8;
    float4 a = ((const float4*)p)[0];
    float4 c = ((const float4*)p)[1];
    float s = a.x + a.y + a.z + a.w + c.x + c.y + c.z + c.w;
    float ss = a.x * a.x + a.y * a.y + a.z * a.z + a.w * a.w +
               c.x * c.x + c.y * c.y + c.z * c.z + c.w * c.w;
#pragma unroll
    for (int off = 1; off < 64; off <<= 1) {
        s += __shfl_xor(s, off, 64);
        ss += __shfl_xor(ss, off, 64);
    }
    const float mu = s * (1.f / 512.f);
    const float var = ss * (1.f / 512.f) - mu * mu;
    const float rstd = 1.f / sqrtf(var + 1e-5f);
    const int c0 = lane * 8;
    float4 g0 = *(const float4*)(gg + c0), g1 = *(const float4*)(gg + c0 + 4);
    float4 b0 = *(const float4*)(bb + c0), b1 = *(const float4*)(bb + c0 + 4);
    float4 o0, o1;
    o0.x = (a.x - mu) * rstd * g0.x + b0.x;
    o0.y = (a.y - mu) * rstd * g0.y + b0.y;
    o0.z = (a.z - mu) * rstd * g0.z + b0.z;
    o0.w = (a.w - mu) * rstd * g0.w + b0.w;
    o1.x = (c.x - mu) * rstd * g1.x + b1.x;
    o1.y = (c.y - mu) * rstd * g1.y + b1.y;
    o1.z = (c.z - mu) * rstd * g1.z + b1.z;
    o1.w = (c.w - mu) * rstd * g1.w + b1.w;
    if constexpr (WF) {
        float* qp = outf + row * DMODEL + c0;
        ((float4*)qp)[0] = o0;
        ((float4*)qp)[1] = o1;
    }
    if constexpr (WB) {
        ushort* bp = outb + row * DMODEL + c0;
        ushort4 u0, u1;
        u0.x = f_to_bf(o0.x); u0.y = f_to_bf(o0.y);
        u0.z = f_to_bf(o0.z); u0.w = f_to_bf(o0.w);
        u1.x = f_to_bf(o1.x); u1.y = f_to_bf(o1.y);
        u1.z = f_to_bf(o1.z); u1.w = f_to_bf(o1.w);
        ((ushort4*)bp)[0] = u0;
        ((ushort4*)bp)[1] = u1;
    }
}

// fp32 -> bf16 (RNE) grid-stride converter.
__global__ __launch_bounds__(256) void cvt_f32_bf16(const float* __restrict__ in,
                                                    ushort* __restrict__ out,
                                                    int n4) {
    int i = blockIdx.x * 256 + threadIdx.x;
    const int stride = gridDim.x * 256;
    for (; i < n4; i += stride) {
        float4 v = ((const float4*)in)[i];
        ushort4 o;
        o.x = f_to_bf(v.x); o.y = f_to_bf(v.y);
        o.z = f_to_bf(v.z); o.w = f_to_bf(v.w);
        ((ushort4*)out)[i] = o;
    }
}

// =====================================================================
// Workspace (single layout; needs ws >= 389 MiB, harness provides 512):
//   ws:  qkv bf16 [N,1536] [0,384) -> h f32 [0,256) -> y2 f32 [0,256)
//        hb bf16 [256,384) (lives over dead qkv tail, until G6)
//        weights bf16 @ [384,389)
//   d_out: xb bf16 [0,128) + ctx bf16 [128,256) -> ff bf16 [0,256)
//          -> final out f32 [0,256)
// Numerics identical to round-2 tight path (h f32, resid x f32, hb bf16).
// =====================================================================
extern "C" void kernel_launch(void* const* d_in, const int* in_sizes, int n_in,
                              void* d_out, int out_size, void* d_ws, size_t ws_size,
                              hipStream_t stream) {
    const float* x    = (const float*)d_in[0];
    const float* wqkv = (const float*)d_in[1];
    const float* bqkv = (const float*)d_in[2];
    const float* wo   = (const float*)d_in[3];
    const float* bo   = (const float*)d_in[4];
    const float* w1   = (const float*)d_in[5];
    const float* b1   = (const float*)d_in[6];
    const float* w2   = (const float*)d_in[7];
    const float* b2   = (const float*)d_in[8];
    const float* g1   = (const float*)d_in[9];
    const float* be1  = (const float*)d_in[10];
    const float* g2   = (const float*)d_in[11];
    const float* be2  = (const float*)d_in[12];
    float* out = (float*)d_out;

    const size_t MiB = 1ull << 20;
    char* ws = (char*)d_ws;
    char* ob = (char*)d_out;

    ushort* qkv   = (ushort*)ws;                 // [0,384) MiB
    float*  h     = (float*)ws;                  // [0,256) after qkv dead
    float*  y2    = (float*)ws;                  // [0,256) after h dead
    ushort* hb    = (ushort*)(ws + 256 * MiB);   // [256,384)
    ushort* wqkvb = (ushort*)(ws + 384 * MiB);
    ushort* wob   = (ushort*)(ws + 386 * MiB);
    ushort* w1b   = (ushort*)(ws + 387 * MiB);
    ushort* w2b   = (ushort*)(ws + 388 * MiB);
    ushort* xb    = (ushort*)ob;                 // d_out [0,128)
    ushort* ctx   = (ushort*)(ob + 128 * MiB);   // d_out [128,256)
    ushort* ff    = (ushort*)ob;                 // d_out [0,256) after G3

    dim3 b256(256), b512(512);
    auto cvt = [&](const float* src, ushort* dst, size_t n) {
        int n4 = (int)(n >> 2);
        int nb = (n4 + 255) / 256;
        if (nb > 4096) nb = 4096;
        cvt_f32_bf16<<<dim3(nb), b256, 0, stream>>>(src, dst, n4);
    };
    cvt(x, xb, (size_t)NTOK * DMODEL);
    cvt(wqkv, wqkvb, 1536 * 512);
    cvt(wo, wob, 512 * 512);
    cvt(w1, w1b, 1024 * 512);
    cvt(w2, w2b, 512 * 1024);

    // 1. qkv = xb @ Wqkv^T + b               [N,1536] bf16
    gemm8p<ushort, float, false, false><<<dim3(512 * 6), b512, 0, stream>>>(
        xb, wqkvb, bqkv, (const float*)nullptr, qkv, NTOK, 1536, 512);
    // 2. block attention (MFMA) -> ctx bf16
    attn_mfma<<<dim3(NB * NHEAD), b256, 0, stream>>>(qkv, ctx);
    // 3. y = x + ctx @ Wo^T + bo -> h f32
    gemm8p<float, float, true, false><<<dim3(512 * 2), b512, 0, stream>>>(
        ctx, wob, bo, x, h, NTOK, 512, 512);
    // 4. h = LN1(y) -> hb bf16
    ln_rows2<false, true><<<dim3(NTOK / 4), b256, 0, stream>>>(h, nullptr, hb, g1, be1);
    // 5. ff = gelu(hb @ W1^T + b1) -> bf16
    gemm8p<ushort, float, false, true><<<dim3(512 * 4), b512, 0, stream>>>(
        hb, w1b, b1, (const float*)nullptr, ff, NTOK, 1024, 512);
    // 6. y2 = hb + ff @ W2^T + b2 -> f32
    gemm8p<float, ushort, true, false><<<dim3(512 * 2), b512, 0, stream>>>(
        ff, w2b, b2, hb, y2, NTOK, 512, 1024);
    // 7. out = LN2(y2)
    ln_rows2<true, false><<<dim3(NTOK / 4), b256, 0, stream>>>(y2, out, nullptr, g2, be2);
}